// Round 1
// baseline (1371.865 us; speedup 1.0000x reference)
//
#include <hip/hip_runtime.h>
#include <math.h>

#define NNODES 50000
#define NEDGES 800000

// ---- monotonic uint encoding for float atomic max ----
__device__ __forceinline__ unsigned enc_f(float f) {
    unsigned u = __float_as_uint(f);
    return (u & 0x80000000u) ? ~u : (u | 0x80000000u);
}
__device__ __forceinline__ float dec_f(unsigned u) {
    return (u & 0x80000000u) ? __uint_as_float(u & 0x7FFFFFFFu)
                             : __uint_as_float(~u);
}
#define ENC_NEG_INF 0x007FFFFFu   // enc(-inf)

// ---- init m (encoded -inf), s (0), acc (0) ----
__global__ void init_layer(unsigned* __restrict__ m, float* __restrict__ s,
                           float* __restrict__ acc, int nh, int nacc) {
    int i = blockIdx.x * blockDim.x + threadIdx.x;
    if (i < nh) { m[i] = ENC_NEG_INF; s[i] = 0.f; }
    if (i < nacc) acc[i] = 0.f;
}

// ---- GEMM (x @ W) fused with attention projections el/er ----
// Block: DOUT threads handles NB nodes. W column per thread, x rows in LDS.
template <int DIN, int DOUT, int H, int NB>
__global__ void gemm_attn(const float* __restrict__ x, const float* __restrict__ W,
                          const float* __restrict__ al, const float* __restrict__ ar,
                          float* __restrict__ feat, float* __restrict__ el,
                          float* __restrict__ er) {
    constexpr int D = DOUT / H;
    __shared__ float xs[NB * DIN];
    const int node0 = blockIdx.x * NB;
    const int d = threadIdx.x;

    for (int idx = d; idx < NB * DIN; idx += DOUT)
        xs[idx] = x[node0 * DIN + idx];
    __syncthreads();

    float accv[NB];
#pragma unroll
    for (int nb = 0; nb < NB; nb++) accv[nb] = 0.f;

    for (int k = 0; k < DIN; k++) {
        float w = W[k * DOUT + d];
#pragma unroll
        for (int nb = 0; nb < NB; nb++) accv[nb] += xs[nb * DIN + k] * w;
    }

    const float alv = al[d], arv = ar[d];
    const int h = d / D;
#pragma unroll
    for (int nb = 0; nb < NB; nb++) {
        float a = accv[nb];
        feat[(node0 + nb) * DOUT + d] = a;
        float pl = a * alv, pr = a * arv;
#pragma unroll
        for (int off = D / 2; off > 0; off >>= 1) {
            pl += __shfl_xor(pl, off);
            pr += __shfl_xor(pr, off);
        }
        if ((d & (D - 1)) == 0) {
            el[(node0 + nb) * H + h] = pl;
            er[(node0 + nb) * H + h] = pr;
        }
    }
}

// ---- per-edge leaky-relu logit + segment max (into m) ----
template <int H>
__global__ void edge_attn_max(const int* __restrict__ src, const int* __restrict__ dst,
                              const float* __restrict__ el, const float* __restrict__ er,
                              float* __restrict__ ebuf, unsigned* __restrict__ m) {
    int t = blockIdx.x * blockDim.x + threadIdx.x;
    if (t >= NEDGES * H) return;
    int eid = t / H, h = t - eid * H;
    int sn = src[eid], dn = dst[eid];
    float v = el[sn * H + h] + er[dn * H + h];
    v = v > 0.f ? v : 0.2f * v;
    ebuf[t] = v;
    atomicMax(&m[dn * H + h], enc_f(v));
}

// ---- per-edge exp(e - m[dst]) + segment sum (into s) ----
template <int H>
__global__ void edge_attn_expsum(const int* __restrict__ dst,
                                 const unsigned* __restrict__ m,
                                 float* __restrict__ ebuf, float* __restrict__ s) {
    int t = blockIdx.x * blockDim.x + threadIdx.x;
    if (t >= NEDGES * H) return;
    int eid = t / H, h = t - eid * H;
    int dh = dst[eid] * H + h;
    float ex = expf(ebuf[t] - dec_f(m[dh]));
    ebuf[t] = ex;
    unsafeAtomicAdd(&s[dh], ex);
}

// ---- per-(edge,dim) weighted message scatter-add ----
template <int DOUT, int H>
__global__ void edge_aggregate(const int* __restrict__ src, const int* __restrict__ dst,
                               const float* __restrict__ ebuf, const float* __restrict__ s,
                               const float* __restrict__ feat, float* __restrict__ acc) {
    constexpr int D = DOUT / H;
    int t = blockIdx.x * blockDim.x + threadIdx.x;
    if (t >= NEDGES * DOUT) return;
    int eid = t / DOUT, d = t - eid * DOUT;
    int h = d / D;
    int sn = src[eid], dn = dst[eid];
    float alpha = ebuf[eid * H + h] / s[dn * H + h];
    unsafeAtomicAdd(&acc[dn * DOUT + d], alpha * feat[sn * DOUT + d]);
}

// ---- bias + ELU into next layer input ----
template <int DOUT>
__global__ void epilogue_elu(const float* __restrict__ acc, const float* __restrict__ b,
                             float* __restrict__ xout) {
    int t = blockIdx.x * blockDim.x + threadIdx.x;
    if (t >= NNODES * DOUT) return;
    float v = acc[t] + b[t & (DOUT - 1)];
    xout[t] = v > 0.f ? v : expm1f(v);
}

// ---- final layer: bias only (mean over 1 head == identity) ----
__global__ void epilogue_final(const float* __restrict__ acc, const float* __restrict__ b,
                               float* __restrict__ out) {
    int t = blockIdx.x * blockDim.x + threadIdx.x;
    if (t >= NNODES * 64) return;
    out[t] = acc[t] + b[t & 63];
}

static inline int cdiv(int a, int b) { return (a + b - 1) / b; }

extern "C" void kernel_launch(void* const* d_in, const int* in_sizes, int n_in,
                              void* d_out, int out_size, void* d_ws, size_t ws_size,
                              hipStream_t stream) {
    const float* h   = (const float*)d_in[0];
    const int*   src = (const int*)d_in[1];
    const int*   dst = (const int*)d_in[2];
    const float* W1  = (const float*)d_in[3];
    const float* al1 = (const float*)d_in[4];
    const float* ar1 = (const float*)d_in[5];
    const float* b1  = (const float*)d_in[6];
    const float* W2  = (const float*)d_in[7];
    const float* al2 = (const float*)d_in[8];
    const float* ar2 = (const float*)d_in[9];
    const float* b2  = (const float*)d_in[10];
    const float* W3  = (const float*)d_in[11];
    const float* al3 = (const float*)d_in[12];
    const float* ar3 = (const float*)d_in[13];
    const float* b3  = (const float*)d_in[14];

    float* ws   = (float*)d_ws;
    float* feat = ws;                     // N*128
    float* acc  = feat + NNODES * 128;    // N*128
    float* x2   = acc + NNODES * 128;     // N*128
    float* x3   = x2 + NNODES * 128;      // N*128
    float* el   = x3 + NNODES * 128;      // N*4
    float* er   = el + NNODES * 4;        // N*4
    float* s    = er + NNODES * 4;        // N*4
    unsigned* m = (unsigned*)(s + NNODES * 4);  // N*4
    float* ebuf = (float*)(m + NNODES * 4);     // E*4

    const dim3 B(256);

    // ---------- layer 1 (H=4, D=32, DOUT=128) ----------
    init_layer<<<cdiv(NNODES * 128, 256), B, 0, stream>>>(m, s, acc, NNODES * 4, NNODES * 128);
    gemm_attn<128, 128, 4, 8><<<NNODES / 8, 128, 0, stream>>>(h, W1, al1, ar1, feat, el, er);
    edge_attn_max<4><<<cdiv(NEDGES * 4, 256), B, 0, stream>>>(src, dst, el, er, ebuf, m);
    edge_attn_expsum<4><<<cdiv(NEDGES * 4, 256), B, 0, stream>>>(dst, m, ebuf, s);
    edge_aggregate<128, 4><<<cdiv(NEDGES * 128, 256), B, 0, stream>>>(src, dst, ebuf, s, feat, acc);
    epilogue_elu<128><<<cdiv(NNODES * 128, 256), B, 0, stream>>>(acc, b1, x2);

    // ---------- layer 2 (H=4, D=32, DOUT=128) ----------
    init_layer<<<cdiv(NNODES * 128, 256), B, 0, stream>>>(m, s, acc, NNODES * 4, NNODES * 128);
    gemm_attn<128, 128, 4, 8><<<NNODES / 8, 128, 0, stream>>>(x2, W2, al2, ar2, feat, el, er);
    edge_attn_max<4><<<cdiv(NEDGES * 4, 256), B, 0, stream>>>(src, dst, el, er, ebuf, m);
    edge_attn_expsum<4><<<cdiv(NEDGES * 4, 256), B, 0, stream>>>(dst, m, ebuf, s);
    edge_aggregate<128, 4><<<cdiv(NEDGES * 128, 256), B, 0, stream>>>(src, dst, ebuf, s, feat, acc);
    epilogue_elu<128><<<cdiv(NNODES * 128, 256), B, 0, stream>>>(acc, b2, x3);

    // ---------- layer 3 (H=1, D=64, DOUT=64) ----------
    init_layer<<<cdiv(NNODES * 64, 256), B, 0, stream>>>(m, s, acc, NNODES * 1, NNODES * 64);
    gemm_attn<128, 64, 1, 8><<<NNODES / 8, 64, 0, stream>>>(x3, W3, al3, ar3, feat, el, er);
    edge_attn_max<1><<<cdiv(NEDGES, 256), B, 0, stream>>>(src, dst, el, er, ebuf, m);
    edge_attn_expsum<1><<<cdiv(NEDGES, 256), B, 0, stream>>>(dst, m, ebuf, s);
    edge_aggregate<64, 1><<<cdiv(NEDGES * 64, 256), B, 0, stream>>>(src, dst, ebuf, s, feat, acc);
    epilogue_final<<<cdiv(NNODES * 64, 256), B, 0, stream>>>(acc, b3, (float*)d_out);
}

// Round 2
// 643.161 us; speedup vs baseline: 2.1330x; 2.1330x over previous
//
#include <hip/hip_runtime.h>
#include <math.h>

#define NNODES 50000
#define NEDGES 800000

static inline int cdiv(int a, int b) { return (a + b - 1) / b; }

// ================= CSR build (once per call; graph shared by all layers) =================

__global__ void zero_deg(int* __restrict__ deg) {
    int i = blockIdx.x * blockDim.x + threadIdx.x;
    if (i < NNODES) deg[i] = 0;
}

__global__ void count_deg(const int* __restrict__ dst, int* __restrict__ deg) {
    int e = blockIdx.x * blockDim.x + threadIdx.x;
    if (e < NEDGES) atomicAdd(&deg[dst[e]], 1);
}

// single-block exclusive scan of deg[0..N) -> rowptr[0..N], also copies to cursor
__global__ void scan_rowptr(const int* __restrict__ deg, int* __restrict__ rowptr,
                            int* __restrict__ cursor) {
    __shared__ int wsum[16];
    __shared__ int wpre[16];
    const int tid = threadIdx.x;
    const int lane = tid & 63, wid = tid >> 6;
    int carry = 0;
    const int ntiles = (NNODES + 1023) / 1024;
    for (int t = 0; t < ntiles; t++) {
        int i = t * 1024 + tid;
        int v = (i < NNODES) ? deg[i] : 0;
        int x = v;
#pragma unroll
        for (int off = 1; off < 64; off <<= 1) {
            int y = __shfl_up(x, off);
            if (lane >= off) x += y;
        }
        if (lane == 63) wsum[wid] = x;
        __syncthreads();
        if (wid == 0) {
            int w = (lane < 16) ? wsum[lane] : 0;
            int xs = w;
#pragma unroll
            for (int off = 1; off < 16; off <<= 1) {
                int y = __shfl_up(xs, off);
                if (lane >= off) xs += y;
            }
            if (lane < 16) wpre[lane] = xs - w;   // exclusive wave prefix
        }
        __syncthreads();
        int excl = carry + wpre[wid] + x - v;
        if (i < NNODES) { rowptr[i] = excl; cursor[i] = excl; }
        carry += wpre[15] + wsum[15];             // tile total (uniform)
        __syncthreads();
    }
    if (tid == 0) rowptr[NNODES] = carry;
}

__global__ void scatter_src(const int* __restrict__ src, const int* __restrict__ dst,
                            int* __restrict__ cursor, int* __restrict__ csr_src) {
    int e = blockIdx.x * blockDim.x + threadIdx.x;
    if (e < NEDGES) {
        int pos = atomicAdd(&cursor[dst[e]], 1);
        csr_src[pos] = src[e];
    }
}

// ================= GEMM (x @ W) fused with attention projections el/er =================
template <int DIN, int DOUT, int H, int NB>
__global__ void gemm_attn(const float* __restrict__ x, const float* __restrict__ W,
                          const float* __restrict__ al, const float* __restrict__ ar,
                          float* __restrict__ feat, float* __restrict__ el,
                          float* __restrict__ er) {
    constexpr int D = DOUT / H;
    __shared__ float xs[NB * DIN];
    const int node0 = blockIdx.x * NB;
    const int d = threadIdx.x;

    for (int idx = d; idx < NB * DIN; idx += DOUT)
        xs[idx] = x[node0 * DIN + idx];
    __syncthreads();

    float accv[NB];
#pragma unroll
    for (int nb = 0; nb < NB; nb++) accv[nb] = 0.f;

    for (int k = 0; k < DIN; k++) {
        float w = W[k * DOUT + d];
#pragma unroll
        for (int nb = 0; nb < NB; nb++) accv[nb] += xs[nb * DIN + k] * w;
    }

    const float alv = al[d], arv = ar[d];
    const int h = d / D;
#pragma unroll
    for (int nb = 0; nb < NB; nb++) {
        float a = accv[nb];
        feat[(node0 + nb) * DOUT + d] = a;
        float pl = a * alv, pr = a * arv;
#pragma unroll
        for (int off = D / 2; off > 0; off >>= 1) {
            pl += __shfl_xor(pl, off);
            pr += __shfl_xor(pr, off);
        }
        if ((d & (D - 1)) == 0) {
            el[(node0 + nb) * H + h] = pl;
            er[(node0 + nb) * H + h] = pr;
        }
    }
}

// ================= per-node softmax + aggregation (one wave per node, no atomics) ========
template <int DOUT, int H>
__global__ void node_aggregate(const int* __restrict__ rowptr, const int* __restrict__ csr_src,
                               const float* __restrict__ el, const float* __restrict__ er,
                               const float* __restrict__ feat, const float* __restrict__ b,
                               float* __restrict__ xout, int do_elu) {
    constexpr int D = DOUT / H;        // dims per head
    constexpr int PL = DOUT / 64;      // dims per lane (2 or 1)
    const int lane = threadIdx.x & 63;
    const int wid = threadIdx.x >> 6;
    const int n = blockIdx.x * (blockDim.x >> 6) + wid;
    if (n >= NNODES) return;
    const int base = rowptr[n];
    const int deg = rowptr[n + 1] - base;

    // er for this node
    float erv[H];
    if constexpr (H == 4) {
        float4 t = *(const float4*)&er[n * 4];
        erv[0] = t.x; erv[1] = t.y; erv[2] = t.z; erv[3] = t.w;
    } else {
        erv[0] = er[n];
    }

    // ---- phase A: per-head max over incoming edges ----
    float mh[H];
#pragma unroll
    for (int h2 = 0; h2 < H; h2++) mh[h2] = -INFINITY;
    for (int j = lane; j < deg; j += 64) {
        int sn = csr_src[base + j];
        if constexpr (H == 4) {
            float4 t = *(const float4*)&el[sn * 4];
            float ev[4] = {t.x, t.y, t.z, t.w};
#pragma unroll
            for (int h2 = 0; h2 < 4; h2++) {
                float e = ev[h2] + erv[h2];
                e = e > 0.f ? e : 0.2f * e;
                mh[h2] = fmaxf(mh[h2], e);
            }
        } else {
            float e = el[sn] + erv[0];
            e = e > 0.f ? e : 0.2f * e;
            mh[0] = fmaxf(mh[0], e);
        }
    }
#pragma unroll
    for (int off = 32; off > 0; off >>= 1)
#pragma unroll
        for (int h2 = 0; h2 < H; h2++)
            mh[h2] = fmaxf(mh[h2], __shfl_xor(mh[h2], off));

    // ---- phase B: unnormalized weights + gather-accumulate ----
    const int h = (lane * PL) / D;      // head owning this lane's dims
    const float mhh = mh[h], erh = erv[h];
    float s = 0.f;
    float acc[PL];
#pragma unroll
    for (int p = 0; p < PL; p++) acc[p] = 0.f;

    for (int j = 0; j < deg; j++) {
        int sn = csr_src[base + j];
        float e = el[sn * H + h] + erh;
        e = e > 0.f ? e : 0.2f * e;
        float pv = expf(e - mhh);
        s += pv;
        const float* frow = &feat[sn * DOUT + lane * PL];
#pragma unroll
        for (int p = 0; p < PL; p++) acc[p] += pv * frow[p];
    }

    float inv = (s > 0.f) ? 1.f / s : 0.f;
#pragma unroll
    for (int p = 0; p < PL; p++) {
        int d = lane * PL + p;
        float v = acc[p] * inv + b[d];
        if (do_elu) v = v > 0.f ? v : expm1f(v);
        xout[n * DOUT + d] = v;
    }
}

// ================= launch =================
extern "C" void kernel_launch(void* const* d_in, const int* in_sizes, int n_in,
                              void* d_out, int out_size, void* d_ws, size_t ws_size,
                              hipStream_t stream) {
    const float* h   = (const float*)d_in[0];
    const int*   src = (const int*)d_in[1];
    const int*   dst = (const int*)d_in[2];
    const float* W1  = (const float*)d_in[3];
    const float* al1 = (const float*)d_in[4];
    const float* ar1 = (const float*)d_in[5];
    const float* b1  = (const float*)d_in[6];
    const float* W2  = (const float*)d_in[7];
    const float* al2 = (const float*)d_in[8];
    const float* ar2 = (const float*)d_in[9];
    const float* b2  = (const float*)d_in[10];
    const float* W3  = (const float*)d_in[11];
    const float* al3 = (const float*)d_in[12];
    const float* ar3 = (const float*)d_in[13];
    const float* b3  = (const float*)d_in[14];

    float* ws   = (float*)d_ws;
    float* feat = ws;                       // N*128
    float* x2   = feat + NNODES * 128;      // N*128
    float* x3   = x2 + NNODES * 128;        // N*128
    float* el   = x3 + NNODES * 128;        // N*4  (16B aligned)
    float* er   = el + NNODES * 4;          // N*4
    int* rowptr  = (int*)(er + NNODES * 4); // N+1
    int* cursor  = rowptr + NNODES + 1;     // N
    int* deg     = cursor + NNODES;         // N
    int* csr_src = deg + NNODES;            // E

    const dim3 B(256);

    // ---- CSR build (graph is layer-invariant) ----
    zero_deg<<<cdiv(NNODES, 256), B, 0, stream>>>(deg);
    count_deg<<<cdiv(NEDGES, 256), B, 0, stream>>>(dst, deg);
    scan_rowptr<<<1, 1024, 0, stream>>>(deg, rowptr, cursor);
    scatter_src<<<cdiv(NEDGES, 256), B, 0, stream>>>(src, dst, cursor, csr_src);

    // ---- layer 1 (H=4, D=32, DOUT=128) ----
    gemm_attn<128, 128, 4, 8><<<NNODES / 8, 128, 0, stream>>>(h, W1, al1, ar1, feat, el, er);
    node_aggregate<128, 4><<<cdiv(NNODES, 4), B, 0, stream>>>(rowptr, csr_src, el, er, feat, b1, x2, 1);

    // ---- layer 2 (H=4, D=32, DOUT=128) ----
    gemm_attn<128, 128, 4, 8><<<NNODES / 8, 128, 0, stream>>>(x2, W2, al2, ar2, feat, el, er);
    node_aggregate<128, 4><<<cdiv(NNODES, 4), B, 0, stream>>>(rowptr, csr_src, el, er, feat, b2, x3, 1);

    // ---- layer 3 (H=1, D=64, DOUT=64) ----
    gemm_attn<128, 64, 1, 8><<<NNODES / 8, 64, 0, stream>>>(x3, W3, al3, ar3, feat, el, er);
    node_aggregate<64, 1><<<cdiv(NNODES, 4), B, 0, stream>>>(rowptr, csr_src, el, er, feat, b3, (float*)d_out, 0);
}

// Round 5
// 497.920 us; speedup vs baseline: 2.7552x; 1.2917x over previous
//
#include <hip/hip_runtime.h>
#include <hip/hip_bf16.h>
#include <math.h>

#define NNODES 50000
#define NEDGES 800000

static inline int cdiv(int a, int b) { return (a + b - 1) / b; }

// ================= CSR build (once per call; graph shared by all layers) =================

__global__ void zero_deg(int* __restrict__ deg) {
    int i = blockIdx.x * blockDim.x + threadIdx.x;
    if (i < NNODES) deg[i] = 0;
}

__global__ void count_deg(const int* __restrict__ dst, int* __restrict__ deg) {
    int e = blockIdx.x * blockDim.x + threadIdx.x;
    if (e < NEDGES) atomicAdd(&deg[dst[e]], 1);
}

// single-block exclusive scan, 4 elems/thread -> rowptr[0..N], cursor copy
__global__ void scan_rowptr(const int* __restrict__ deg, int* __restrict__ rowptr,
                            int* __restrict__ cursor) {
    __shared__ int wsum[16];
    __shared__ int wpre[16];
    const int tid = threadIdx.x;
    const int lane = tid & 63, wid = tid >> 6;
    int carry = 0;
    const int ntiles = (NNODES + 4095) / 4096;
    for (int t = 0; t < ntiles; t++) {
        int i0 = t * 4096 + tid * 4;
        int4 v = make_int4(0, 0, 0, 0);
        if (i0 < NNODES) v = *(const int4*)&deg[i0];   // NNODES % 4 == 0
        int lsum = v.x + v.y + v.z + v.w;
        int x = lsum;
#pragma unroll
        for (int off = 1; off < 64; off <<= 1) {
            int y = __shfl_up(x, off);
            if (lane >= off) x += y;
        }
        if (lane == 63) wsum[wid] = x;
        __syncthreads();
        if (wid == 0) {
            int w = (lane < 16) ? wsum[lane] : 0;
            int xs = w;
#pragma unroll
            for (int off = 1; off < 16; off <<= 1) {
                int y = __shfl_up(xs, off);
                if (lane >= off) xs += y;
            }
            if (lane < 16) wpre[lane] = xs - w;   // exclusive wave prefix
        }
        __syncthreads();
        int excl = carry + wpre[wid] + x - lsum;
        if (i0 < NNODES) {
            int4 r;
            r.x = excl; r.y = r.x + v.x; r.z = r.y + v.y; r.w = r.z + v.z;
            *(int4*)&rowptr[i0] = r;
            *(int4*)&cursor[i0] = r;
        }
        carry += wpre[15] + wsum[15];
        __syncthreads();
    }
    if (tid == 0) rowptr[NNODES] = carry;
}

__global__ void scatter_src(const int* __restrict__ src, const int* __restrict__ dst,
                            int* __restrict__ cursor, int* __restrict__ csr_src) {
    int e = blockIdx.x * blockDim.x + threadIdx.x;
    if (e < NEDGES) {
        int pos = atomicAdd(&cursor[dst[e]], 1);
        csr_src[pos] = src[e];
    }
}

// ================= GEMM (x @ W) + attention projections; feat written bf16 =================
template <int DIN, int DOUT, int H, int NB>
__global__ void gemm_attn(const float* __restrict__ x, const float* __restrict__ W,
                          const float* __restrict__ al, const float* __restrict__ ar,
                          __hip_bfloat16* __restrict__ feat, float* __restrict__ el,
                          float* __restrict__ er) {
    constexpr int D = DOUT / H;
    __shared__ float xs[NB * DIN];
    const int node0 = blockIdx.x * NB;
    const int d = threadIdx.x;

    // float4 staging of NB input rows
    const float4* xg = (const float4*)&x[node0 * DIN];
    float4* xs4 = (float4*)xs;
    for (int idx = d; idx < NB * DIN / 4; idx += DOUT) xs4[idx] = xg[idx];
    __syncthreads();

    float accv[NB];
#pragma unroll
    for (int nb = 0; nb < NB; nb++) accv[nb] = 0.f;

    for (int k = 0; k < DIN; k++) {
        float w = W[k * DOUT + d];
#pragma unroll
        for (int nb = 0; nb < NB; nb++) accv[nb] += xs[nb * DIN + k] * w;
    }

    const float alv = al[d], arv = ar[d];
    const int h = d / D;
#pragma unroll
    for (int nb = 0; nb < NB; nb++) {
        float a = accv[nb];
        feat[(node0 + nb) * DOUT + d] = __float2bfloat16(a);
        float pl = a * alv, pr = a * arv;
#pragma unroll
        for (int off = D / 2; off > 0; off >>= 1) {
            pl += __shfl_xor(pl, off);
            pr += __shfl_xor(pr, off);
        }
        if ((d & (D - 1)) == 0) {
            el[(node0 + nb) * H + h] = pl;
            er[(node0 + nb) * H + h] = pr;
        }
    }
}

// ========== per-node softmax + aggregation: single pass, no max, bf16 gathers ==========
template <int DOUT, int H>
__global__ void node_aggregate(const int* __restrict__ rowptr, const int* __restrict__ csr_src,
                               const float* __restrict__ el, const float* __restrict__ er,
                               const __hip_bfloat16* __restrict__ feat,
                               const float* __restrict__ b,
                               float* __restrict__ xout, int do_elu) {
    constexpr int D = DOUT / H;        // dims per head
    constexpr int PL = DOUT / 64;      // dims per lane (2 or 1)
    const int lane = threadIdx.x & 63;
    const int wid = threadIdx.x >> 6;
    const int n = blockIdx.x * (blockDim.x >> 6) + wid;
    if (n >= NNODES) return;
    const int base = rowptr[n];
    const int deg = rowptr[n + 1] - base;

    const int h = (lane * PL) / D;     // head owning this lane's dims
    const float erh = er[n * H + h];

    float s = 0.f;
    float acc[PL];
#pragma unroll
    for (int p = 0; p < PL; p++) acc[p] = 0.f;

    int j = 0;
    for (; j + 1 < deg; j += 2) {
        int sn0 = csr_src[base + j];
        int sn1 = csr_src[base + j + 1];
        float e0 = el[sn0 * H + h] + erh;
        float e1 = el[sn1 * H + h] + erh;
        e0 = e0 > 0.f ? e0 : 0.2f * e0;
        e1 = e1 > 0.f ? e1 : 0.2f * e1;
        float p0 = __expf(e0);
        float p1 = __expf(e1);
        s += p0 + p1;
        const __hip_bfloat16* f0 = &feat[sn0 * DOUT + lane * PL];
        const __hip_bfloat16* f1 = &feat[sn1 * DOUT + lane * PL];
        if constexpr (PL == 2) {
            float2 a0 = __bfloat1622float2(*(const __hip_bfloat162*)f0);
            float2 a1 = __bfloat1622float2(*(const __hip_bfloat162*)f1);
            acc[0] += p0 * a0.x + p1 * a1.x;
            acc[1] += p0 * a0.y + p1 * a1.y;
        } else {
            acc[0] += p0 * __bfloat162float(f0[0]) + p1 * __bfloat162float(f1[0]);
        }
    }
    if (j < deg) {
        int sn0 = csr_src[base + j];
        float e0 = el[sn0 * H + h] + erh;
        e0 = e0 > 0.f ? e0 : 0.2f * e0;
        float p0 = __expf(e0);
        s += p0;
        const __hip_bfloat16* f0 = &feat[sn0 * DOUT + lane * PL];
        if constexpr (PL == 2) {
            float2 a0 = __bfloat1622float2(*(const __hip_bfloat162*)f0);
            acc[0] += p0 * a0.x;
            acc[1] += p0 * a0.y;
        } else {
            acc[0] += p0 * __bfloat162float(f0[0]);
        }
    }

    float inv = (s > 0.f) ? 1.f / s : 0.f;
#pragma unroll
    for (int p = 0; p < PL; p++) {
        int d = lane * PL + p;
        float v = acc[p] * inv + b[d];
        if (do_elu) v = v > 0.f ? v : expm1f(v);
        xout[n * DOUT + d] = v;
    }
}

// ================= launch =================
extern "C" void kernel_launch(void* const* d_in, const int* in_sizes, int n_in,
                              void* d_out, int out_size, void* d_ws, size_t ws_size,
                              hipStream_t stream) {
    const float* h   = (const float*)d_in[0];
    const int*   src = (const int*)d_in[1];
    const int*   dst = (const int*)d_in[2];
    const float* W1  = (const float*)d_in[3];
    const float* al1 = (const float*)d_in[4];
    const float* ar1 = (const float*)d_in[5];
    const float* b1  = (const float*)d_in[6];
    const float* W2  = (const float*)d_in[7];
    const float* al2 = (const float*)d_in[8];
    const float* ar2 = (const float*)d_in[9];
    const float* b2  = (const float*)d_in[10];
    const float* W3  = (const float*)d_in[11];
    const float* al3 = (const float*)d_in[12];
    const float* ar3 = (const float*)d_in[13];
    const float* b3  = (const float*)d_in[14];

    float* ws = (float*)d_ws;
    __hip_bfloat16* feat = (__hip_bfloat16*)ws;     // N*128 bf16 = N*64 float slots
    float* x2 = ws + NNODES * 64;                   // N*128
    float* x3 = x2 + NNODES * 128;                  // N*128
    float* el = x3 + NNODES * 128;                  // N*4
    float* er = el + NNODES * 4;                    // N*4
    int* deg     = (int*)(er + NNODES * 4);         // N        (16B aligned)
    int* rowptr  = deg + NNODES;                    // N+1 (padded to N+4)
    int* cursor  = rowptr + NNODES + 4;             // N        (16B aligned)
    int* csr_src = cursor + NNODES;                 // E

    const dim3 B(256);

    // ---- CSR build (graph is layer-invariant) ----
    zero_deg<<<cdiv(NNODES, 256), B, 0, stream>>>(deg);
    count_deg<<<cdiv(NEDGES, 256), B, 0, stream>>>(dst, deg);
    scan_rowptr<<<1, 1024, 0, stream>>>(deg, rowptr, cursor);
    scatter_src<<<cdiv(NEDGES, 256), B, 0, stream>>>(src, dst, cursor, csr_src);

    // ---- layer 1 (H=4, D=32, DOUT=128) ----
    gemm_attn<128, 128, 4, 16><<<NNODES / 16, 128, 0, stream>>>(h, W1, al1, ar1, feat, el, er);
    node_aggregate<128, 4><<<cdiv(NNODES, 4), B, 0, stream>>>(rowptr, csr_src, el, er, feat, b1, x2, 1);

    // ---- layer 2 (H=4, D=32, DOUT=128) ----
    gemm_attn<128, 128, 4, 16><<<NNODES / 16, 128, 0, stream>>>(x2, W2, al2, ar2, feat, el, er);
    node_aggregate<128, 4><<<cdiv(NNODES, 4), B, 0, stream>>>(rowptr, csr_src, el, er, feat, b2, x3, 1);

    // ---- layer 3 (H=1, D=64, DOUT=64) ----
    gemm_attn<128, 64, 1, 16><<<NNODES / 16, 64, 0, stream>>>(x3, W3, al3, ar3, feat, el, er);
    node_aggregate<64, 1><<<cdiv(NNODES, 4), B, 0, stream>>>(rowptr, csr_src, el, er, feat, b3, (float*)d_out, 0);
}

// Round 7
// 462.675 us; speedup vs baseline: 2.9651x; 1.0762x over previous
//
#include <hip/hip_runtime.h>
#include <hip/hip_bf16.h>
#include <math.h>

#define NNODES 50000
#define NEDGES 800000

static inline int cdiv(int a, int b) { return (a + b - 1) / b; }

// ================= CSR build (once per call; graph shared by all layers) =================

__global__ void zero_deg(int* __restrict__ deg) {
    int i = blockIdx.x * blockDim.x + threadIdx.x;
    if (i < NNODES) deg[i] = 0;
}

__global__ void count_deg(const int* __restrict__ dst, int* __restrict__ deg) {
    int e = blockIdx.x * blockDim.x + threadIdx.x;
    if (e < NEDGES) atomicAdd(&deg[dst[e]], 1);
}

// single-block exclusive scan, 4 elems/thread -> rowptr[0..N], cursor copy
__global__ void scan_rowptr(const int* __restrict__ deg, int* __restrict__ rowptr,
                            int* __restrict__ cursor) {
    __shared__ int wsum[16];
    __shared__ int wpre[16];
    const int tid = threadIdx.x;
    const int lane = tid & 63, wid = tid >> 6;
    int carry = 0;
    const int ntiles = (NNODES + 4095) / 4096;
    for (int t = 0; t < ntiles; t++) {
        int i0 = t * 4096 + tid * 4;
        int4 v = make_int4(0, 0, 0, 0);
        if (i0 < NNODES) v = *(const int4*)&deg[i0];   // NNODES % 4 == 0
        int lsum = v.x + v.y + v.z + v.w;
        int x = lsum;
#pragma unroll
        for (int off = 1; off < 64; off <<= 1) {
            int y = __shfl_up(x, off);
            if (lane >= off) x += y;
        }
        if (lane == 63) wsum[wid] = x;
        __syncthreads();
        if (wid == 0) {
            int w = (lane < 16) ? wsum[lane] : 0;
            int xs = w;
#pragma unroll
            for (int off = 1; off < 16; off <<= 1) {
                int y = __shfl_up(xs, off);
                if (lane >= off) xs += y;
            }
            if (lane < 16) wpre[lane] = xs - w;   // exclusive wave prefix
        }
        __syncthreads();
        int excl = carry + wpre[wid] + x - lsum;
        if (i0 < NNODES) {
            int4 r;
            r.x = excl; r.y = r.x + v.x; r.z = r.y + v.y; r.w = r.z + v.z;
            *(int4*)&rowptr[i0] = r;
            *(int4*)&cursor[i0] = r;
        }
        carry += wpre[15] + wsum[15];
        __syncthreads();
    }
    if (tid == 0) rowptr[NNODES] = carry;
}

__global__ void scatter_src(const int* __restrict__ src, const int* __restrict__ dst,
                            int* __restrict__ cursor, int* __restrict__ csr_src) {
    int e = blockIdx.x * blockDim.x + threadIdx.x;
    if (e < NEDGES) {
        int pos = atomicAdd(&cursor[dst[e]], 1);
        csr_src[pos] = src[e];
    }
}

// ====== register-tiled fp32 GEMM (x @ W) + attention projections; feat written bf16 ======
// Block: 256 threads, BM=64 nodes, full DOUT cols, BK=32. x staged TRANSPOSED in LDS
// (xs[k][node], pad 68) so compute reads are ds_read_b128, not 16x broadcast b32.
template <int DIN, int DOUT, int H>
__global__ __launch_bounds__(256) void gemm_attn_rt(
    const float* __restrict__ x, const float* __restrict__ W,
    const float* __restrict__ al, const float* __restrict__ ar,
    __hip_bfloat16* __restrict__ feat, float* __restrict__ el,
    float* __restrict__ er) {
    constexpr int BM = 64, BK = 32;
    constexpr int CG = DOUT / 4;          // col groups (32 or 16)
    constexpr int NG = 256 / CG;          // node groups (8 or 16)
    constexpr int NT = BM / NG;           // nodes per thread (8 or 4)
    constexpr int D = DOUT / H;           // dims per head
    constexpr int CPH = D / 4;            // col-groups per head (8 or 16)
    constexpr int XP = BM + 4;            // padded x_t stride (16B-aligned rows)

    __shared__ float xs[BK][XP];
    __shared__ float ws[BK][DOUT];

    const int t = threadIdx.x;
    const int node0 = blockIdx.x * BM;
    const int cg = t % CG, ng = t / CG;
    const int c0 = cg * 4, n0 = ng * NT;

    float acc[NT][4];
#pragma unroll
    for (int i = 0; i < NT; i++)
#pragma unroll
        for (int j = 0; j < 4; j++) acc[i][j] = 0.f;

    for (int k0 = 0; k0 < DIN; k0 += BK) {
        // stage W k-slice (coalesced float4)
        for (int i = t * 4; i < BK * DOUT; i += 256 * 4) {
            int kk = i / DOUT, c = i % DOUT;
            *(float4*)&ws[kk][c] = *(const float4*)&W[(k0 + kk) * DOUT + c];
        }
        // stage x transposed (coalesced read, minor LDS write conflict — staging only)
        for (int i = t; i < BK * BM; i += 256) {
            int kk = i & (BK - 1), nd = i >> 5;
            int node = node0 + nd;
            xs[kk][nd] = (node < NNODES) ? x[node * DIN + k0 + kk] : 0.f;
        }
        __syncthreads();
        for (int k = 0; k < BK; k++) {
            const float4 wv = *(const float4*)&ws[k][c0];
#pragma unroll
            for (int i0 = 0; i0 < NT; i0 += 4) {
                const float4 xv = *(const float4*)&xs[k][n0 + i0];
                acc[i0 + 0][0] += xv.x * wv.x; acc[i0 + 0][1] += xv.x * wv.y;
                acc[i0 + 0][2] += xv.x * wv.z; acc[i0 + 0][3] += xv.x * wv.w;
                acc[i0 + 1][0] += xv.y * wv.x; acc[i0 + 1][1] += xv.y * wv.y;
                acc[i0 + 1][2] += xv.y * wv.z; acc[i0 + 1][3] += xv.y * wv.w;
                acc[i0 + 2][0] += xv.z * wv.x; acc[i0 + 2][1] += xv.z * wv.y;
                acc[i0 + 2][2] += xv.z * wv.z; acc[i0 + 2][3] += xv.z * wv.w;
                acc[i0 + 3][0] += xv.w * wv.x; acc[i0 + 3][1] += xv.w * wv.y;
                acc[i0 + 3][2] += xv.w * wv.z; acc[i0 + 3][3] += xv.w * wv.w;
            }
        }
        __syncthreads();
    }

    // epilogue: feat (bf16x4), el/er via shfl-reduce over the head's col-groups
    const float4 alv = *(const float4*)&al[c0];
    const float4 arv = *(const float4*)&ar[c0];
    const int head = c0 / D;
#pragma unroll
    for (int i = 0; i < NT; i++) {
        const int node = node0 + n0 + i;
        float ax = acc[i][0], ay = acc[i][1], az = acc[i][2], aw = acc[i][3];
        if (node < NNODES) {
            ushort4 u;
            u.x = __bfloat16_as_ushort(__float2bfloat16(ax));
            u.y = __bfloat16_as_ushort(__float2bfloat16(ay));
            u.z = __bfloat16_as_ushort(__float2bfloat16(az));
            u.w = __bfloat16_as_ushort(__float2bfloat16(aw));
            *(ushort4*)&feat[node * DOUT + c0] = u;
        }
        float pl = ax * alv.x + ay * alv.y + az * alv.z + aw * alv.w;
        float pr = ax * arv.x + ay * arv.y + az * arv.z + aw * arv.w;
#pragma unroll
        for (int off = CPH / 2; off > 0; off >>= 1) {
            pl += __shfl_xor(pl, off);
            pr += __shfl_xor(pr, off);
        }
        if ((cg % CPH) == 0 && node < NNODES) {
            el[node * H + head] = pl;
            er[node * H + head] = pr;
        }
    }
}

// ========== per-node softmax + aggregation v2: lane-parallel exp, LDS p-broadcast ==========
// One wave per node. Per 64-edge chunk: lanes load csr_src + el in parallel, compute
// exp ONCE per (edge,head), stash p in per-wave LDS; main loop is independent feat
// gathers + broadcast p read -> latency well hidden. s accumulated lane-parallel.
template <int DOUT, int H>
__global__ __launch_bounds__(256) void node_aggregate2(
    const int* __restrict__ rowptr, const int* __restrict__ csr_src,
    const float* __restrict__ el, const float* __restrict__ er,
    const __hip_bfloat16* __restrict__ feat, const float* __restrict__ b,
    float* __restrict__ xout, int do_elu) {
    constexpr int D = DOUT / H;        // dims per head
    constexpr int PL = DOUT / 64;      // dims per lane (2 or 1)
    __shared__ float plds[4][64 * H];

    const int lane = threadIdx.x & 63;
    const int wid = threadIdx.x >> 6;
    const int n = blockIdx.x * 4 + wid;
    if (n >= NNODES) return;
    const int base = rowptr[n];
    const int deg = rowptr[n + 1] - base;

    const int h = (lane * PL) / D;

    float erv[H];
    if constexpr (H == 4) {
        float4 t = *(const float4*)&er[n * 4];
        erv[0] = t.x; erv[1] = t.y; erv[2] = t.z; erv[3] = t.w;
    } else {
        erv[0] = er[n];
    }

    float sacc[H];
#pragma unroll
    for (int q = 0; q < H; q++) sacc[q] = 0.f;
    float acc[PL];
#pragma unroll
    for (int p = 0; p < PL; p++) acc[p] = 0.f;

    for (int c0 = 0; c0 < deg; c0 += 64) {
        const int cnt = min(64, deg - c0);
        int sn = 0;
        float p4[H];
#pragma unroll
        for (int q = 0; q < H; q++) p4[q] = 0.f;
        if (lane < cnt) {
            sn = csr_src[base + c0 + lane];
            if constexpr (H == 4) {
                float4 t = *(const float4*)&el[sn * 4];
                float ev[4] = {t.x, t.y, t.z, t.w};
#pragma unroll
                for (int q = 0; q < 4; q++) {
                    float e = ev[q] + erv[q];
                    e = e > 0.f ? e : 0.2f * e;
                    p4[q] = __expf(e);
                    sacc[q] += p4[q];
                }
            } else {
                float e = el[sn] + erv[0];
                e = e > 0.f ? e : 0.2f * e;
                p4[0] = __expf(e);
                sacc[0] += p4[0];
            }
        }
        if constexpr (H == 4) {
            float4 w = {p4[0], p4[1], p4[2], p4[3]};
            *(float4*)&plds[wid][lane * 4] = w;
        } else {
            plds[wid][lane] = p4[0];
        }
        // same-wave LDS RAW: compiler inserts lgkmcnt wait; no barrier needed
        for (int j = 0; j < cnt; j++) {
            int snj = __shfl(sn, j);
            float pj = plds[wid][j * H + h];
            const __hip_bfloat16* f = &feat[snj * DOUT + lane * PL];
            if constexpr (PL == 2) {
                float2 a = __bfloat1622float2(*(const __hip_bfloat162*)f);
                acc[0] += pj * a.x;
                acc[1] += pj * a.y;
            } else {
                acc[0] += pj * __bfloat162float(f[0]);
            }
        }
    }

    // reduce s across lanes (butterfly); every lane ends with full sums
#pragma unroll
    for (int off = 32; off > 0; off >>= 1)
#pragma unroll
        for (int q = 0; q < H; q++) sacc[q] += __shfl_xor(sacc[q], off);
    const float s = sacc[h];
    const float inv = (s > 0.f) ? 1.f / s : 0.f;

#pragma unroll
    for (int p = 0; p < PL; p++) {
        int d = lane * PL + p;
        float v = acc[p] * inv + b[d];
        if (do_elu) v = v > 0.f ? v : expm1f(v);
        xout[n * DOUT + d] = v;
    }
}

// ================= launch =================
extern "C" void kernel_launch(void* const* d_in, const int* in_sizes, int n_in,
                              void* d_out, int out_size, void* d_ws, size_t ws_size,
                              hipStream_t stream) {
    const float* h   = (const float*)d_in[0];
    const int*   src = (const int*)d_in[1];
    const int*   dst = (const int*)d_in[2];
    const float* W1  = (const float*)d_in[3];
    const float* al1 = (const float*)d_in[4];
    const float* ar1 = (const float*)d_in[5];
    const float* b1  = (const float*)d_in[6];
    const float* W2  = (const float*)d_in[7];
    const float* al2 = (const float*)d_in[8];
    const float* ar2 = (const float*)d_in[9];
    const float* b2  = (const float*)d_in[10];
    const float* W3  = (const float*)d_in[11];
    const float* al3 = (const float*)d_in[12];
    const float* ar3 = (const float*)d_in[13];
    const float* b3  = (const float*)d_in[14];

    float* ws = (float*)d_ws;
    __hip_bfloat16* feat = (__hip_bfloat16*)ws;     // N*128 bf16 = N*64 float slots
    float* x2 = ws + NNODES * 64;                   // N*128
    float* x3 = x2 + NNODES * 128;                  // N*128
    float* el = x3 + NNODES * 128;                  // N*4
    float* er = el + NNODES * 4;                    // N*4
    int* deg     = (int*)(er + NNODES * 4);         // N        (16B aligned)
    int* rowptr  = deg + NNODES;                    // N+1 (padded to N+4)
    int* cursor  = rowptr + NNODES + 4;             // N        (16B aligned)
    int* csr_src = cursor + NNODES;                 // E

    const dim3 B(256);

    // ---- CSR build (graph is layer-invariant) ----
    zero_deg<<<cdiv(NNODES, 256), B, 0, stream>>>(deg);
    count_deg<<<cdiv(NEDGES, 256), B, 0, stream>>>(dst, deg);
    scan_rowptr<<<1, 1024, 0, stream>>>(deg, rowptr, cursor);
    scatter_src<<<cdiv(NEDGES, 256), B, 0, stream>>>(src, dst, cursor, csr_src);

    // ---- layer 1 (H=4, D=32, DOUT=128) ----
    gemm_attn_rt<128, 128, 4><<<cdiv(NNODES, 64), B, 0, stream>>>(h, W1, al1, ar1, feat, el, er);
    node_aggregate2<128, 4><<<cdiv(NNODES, 4), B, 0, stream>>>(rowptr, csr_src, el, er, feat, b1, x2, 1);

    // ---- layer 2 (H=4, D=32, DOUT=128) ----
    gemm_attn_rt<128, 128, 4><<<cdiv(NNODES, 64), B, 0, stream>>>(x2, W2, al2, ar2, feat, el, er);
    node_aggregate2<128, 4><<<cdiv(NNODES, 4), B, 0, stream>>>(rowptr, csr_src, el, er, feat, b2, x3, 1);

    // ---- layer 3 (H=1, D=64, DOUT=64) ----
    gemm_attn_rt<128, 64, 1><<<cdiv(NNODES, 64), B, 0, stream>>>(x3, W3, al3, ar3, feat, el, er);
    node_aggregate2<64, 1><<<cdiv(NNODES, 4), B, 0, stream>>>(rowptr, csr_src, el, er, feat, b3, (float*)d_out, 0);
}

// Round 11
// 432.795 us; speedup vs baseline: 3.1698x; 1.0690x over previous
//
#include <hip/hip_runtime.h>
#include <hip/hip_bf16.h>
#include <math.h>

#define NNODES 50000
#define NEDGES 800000

static inline int cdiv(int a, int b) { return (a + b - 1) / b; }

// ================= CSR build (once per call; graph shared by all layers) =================

__global__ void zero_deg(int* __restrict__ deg) {
    int i = blockIdx.x * blockDim.x + threadIdx.x;
    if (i < NNODES) deg[i] = 0;
}

__global__ void count_deg(const int* __restrict__ dst, int* __restrict__ deg) {
    int e = blockIdx.x * blockDim.x + threadIdx.x;
    if (e < NEDGES) atomicAdd(&deg[dst[e]], 1);
}

// single-block exclusive scan, 4 elems/thread -> rowptr[0..N], cursor copy
__global__ void scan_rowptr(const int* __restrict__ deg, int* __restrict__ rowptr,
                            int* __restrict__ cursor) {
    __shared__ int wsum[16];
    __shared__ int wpre[16];
    const int tid = threadIdx.x;
    const int lane = tid & 63, wid = tid >> 6;
    int carry = 0;
    const int ntiles = (NNODES + 4095) / 4096;
    for (int t = 0; t < ntiles; t++) {
        int i0 = t * 4096 + tid * 4;
        int4 v = make_int4(0, 0, 0, 0);
        if (i0 < NNODES) v = *(const int4*)&deg[i0];   // NNODES % 4 == 0
        int lsum = v.x + v.y + v.z + v.w;
        int x = lsum;
#pragma unroll
        for (int off = 1; off < 64; off <<= 1) {
            int y = __shfl_up(x, off);
            if (lane >= off) x += y;
        }
        if (lane == 63) wsum[wid] = x;
        __syncthreads();
        if (wid == 0) {
            int w = (lane < 16) ? wsum[lane] : 0;
            int xs = w;
#pragma unroll
            for (int off = 1; off < 16; off <<= 1) {
                int y = __shfl_up(xs, off);
                if (lane >= off) xs += y;
            }
            if (lane < 16) wpre[lane] = xs - w;   // exclusive wave prefix
        }
        __syncthreads();
        int excl = carry + wpre[wid] + x - lsum;
        if (i0 < NNODES) {
            int4 r;
            r.x = excl; r.y = r.x + v.x; r.z = r.y + v.y; r.w = r.z + v.z;
            *(int4*)&rowptr[i0] = r;
            *(int4*)&cursor[i0] = r;
        }
        carry += wpre[15] + wsum[15];
        __syncthreads();
    }
    if (tid == 0) rowptr[NNODES] = carry;
}

__global__ void scatter_src(const int* __restrict__ src, const int* __restrict__ dst,
                            int* __restrict__ cursor, int* __restrict__ csr_src) {
    int e = blockIdx.x * blockDim.x + threadIdx.x;
    if (e < NEDGES) {
        int pos = atomicAdd(&cursor[dst[e]], 1);
        csr_src[pos] = src[e];
    }
}

// ====== register-tiled fp32 GEMM (x @ W) + attention projections; feat written bf16 ======
// Block: 256 threads, BM=128 nodes, BK=32. 8x8 (or 4x8) register tile per thread:
// per k-step 4x ds_read_b128 feed 64 FMA -> LDS pipe not the bottleneck.
template <int DOUT, int H>
__global__ __launch_bounds__(256) void gemm_attn_rt2(
    const float* __restrict__ x, const float* __restrict__ W,
    const float* __restrict__ al, const float* __restrict__ ar,
    __hip_bfloat16* __restrict__ feat, float* __restrict__ el,
    float* __restrict__ er) {
    constexpr int BM = 128, BK = 32;
    constexpr int NC = 8;                 // cols per thread
    constexpr int CG = DOUT / NC;         // col groups (16 or 8)
    constexpr int NG = 256 / CG;          // node groups (16 or 32)
    constexpr int NT = BM / NG;           // nodes per thread (8 or 4)
    constexpr int D = DOUT / H;           // dims per head
    constexpr int CPH = D / NC;           // col-groups per head (4 or 8)
    constexpr int XP = BM + 4;            // padded x_t stride

    __shared__ float xs[BK][XP];
    __shared__ float ws[BK][DOUT];

    const int t = threadIdx.x;
    const int node0 = blockIdx.x * BM;
    const int cg = t % CG, ng = t / CG;
    const int c0 = cg * NC, n0 = ng * NT;

    float acc[NT][NC];
#pragma unroll
    for (int i = 0; i < NT; i++)
#pragma unroll
        for (int j = 0; j < NC; j++) acc[i][j] = 0.f;

    for (int k0 = 0; k0 < 128; k0 += BK) {
        // stage W k-slice (coalesced float4)
        for (int i = t * 4; i < BK * DOUT; i += 256 * 4) {
            int kk = i / DOUT, c = i % DOUT;
            *(float4*)&ws[kk][c] = *(const float4*)&W[(k0 + kk) * DOUT + c];
        }
        // stage x transposed (coalesced read)
        for (int i = t; i < BK * BM; i += 256) {
            int kk = i & (BK - 1), nd = i >> 5;
            int node = node0 + nd;
            xs[kk][nd] = (node < NNODES) ? x[node * 128 + k0 + kk] : 0.f;
        }
        __syncthreads();
        for (int k = 0; k < BK; k++) {
            const float4 wa = *(const float4*)&ws[k][c0];
            const float4 wb = *(const float4*)&ws[k][c0 + 4];
            float wv[NC] = {wa.x, wa.y, wa.z, wa.w, wb.x, wb.y, wb.z, wb.w};
#pragma unroll
            for (int i0 = 0; i0 < NT; i0 += 4) {
                const float4 xv = *(const float4*)&xs[k][n0 + i0];
                float xvv[4] = {xv.x, xv.y, xv.z, xv.w};
#pragma unroll
                for (int ii = 0; ii < 4; ii++)
#pragma unroll
                    for (int q = 0; q < NC; q++)
                        acc[i0 + ii][q] += xvv[ii] * wv[q];
            }
        }
        __syncthreads();
    }

    // epilogue: feat (bf16x8), el/er via shfl-reduce over the head's col-groups
    const float4 ala = *(const float4*)&al[c0];
    const float4 alb = *(const float4*)&al[c0 + 4];
    const float4 ara = *(const float4*)&ar[c0];
    const float4 arb = *(const float4*)&ar[c0 + 4];
    const float alv[NC] = {ala.x, ala.y, ala.z, ala.w, alb.x, alb.y, alb.z, alb.w};
    const float arv[NC] = {ara.x, ara.y, ara.z, ara.w, arb.x, arb.y, arb.z, arb.w};
    const int head = c0 / D;
#pragma unroll
    for (int i = 0; i < NT; i++) {
        const int node = node0 + n0 + i;
        float pl = 0.f, pr = 0.f;
        if (node < NNODES) {
            ushort4 u0, u1;
            u0.x = __bfloat16_as_ushort(__float2bfloat16(acc[i][0]));
            u0.y = __bfloat16_as_ushort(__float2bfloat16(acc[i][1]));
            u0.z = __bfloat16_as_ushort(__float2bfloat16(acc[i][2]));
            u0.w = __bfloat16_as_ushort(__float2bfloat16(acc[i][3]));
            u1.x = __bfloat16_as_ushort(__float2bfloat16(acc[i][4]));
            u1.y = __bfloat16_as_ushort(__float2bfloat16(acc[i][5]));
            u1.z = __bfloat16_as_ushort(__float2bfloat16(acc[i][6]));
            u1.w = __bfloat16_as_ushort(__float2bfloat16(acc[i][7]));
            *(ushort4*)&feat[node * DOUT + c0] = u0;
            *(ushort4*)&feat[node * DOUT + c0 + 4] = u1;
        }
#pragma unroll
        for (int q = 0; q < NC; q++) {
            pl += acc[i][q] * alv[q];
            pr += acc[i][q] * arv[q];
        }
#pragma unroll
        for (int off = CPH / 2; off > 0; off >>= 1) {
            pl += __shfl_xor(pl, off);
            pr += __shfl_xor(pr, off);
        }
        if ((cg % CPH) == 0 && node < NNODES) {
            el[node * H + head] = pl;
            er[node * H + head] = pr;
        }
    }
}

// ========== per-node softmax + aggregation (no atomics, 4x unroll, fp32 out) ==========
template <int DOUT, int H>
__global__ __launch_bounds__(256) void node_aggregate3(
    const int* __restrict__ rowptr, const int* __restrict__ csr_src,
    const float* __restrict__ el, const float* __restrict__ er,
    const __hip_bfloat16* __restrict__ feat, const float* __restrict__ b,
    float* __restrict__ xout, int do_elu) {
    constexpr int D = DOUT / H;        // dims per head
    constexpr int PL = DOUT / 64;      // dims per lane (2 or 1)
    const int lane = threadIdx.x & 63;
    const int wid = threadIdx.x >> 6;
    const int n = blockIdx.x * 4 + wid;
    if (n >= NNODES) return;
    const int base = rowptr[n];
    const int deg = rowptr[n + 1] - base;

    const int h = (lane * PL) / D;     // head owning this lane's dims
    const float erh = er[n * H + h];
    const int* cs = &csr_src[base];

    float s = 0.f;
    float a0 = 0.f, a1 = 0.f;

    int j = 0;
    for (; j + 3 < deg; j += 4) {
        int sn0 = cs[j], sn1 = cs[j + 1], sn2 = cs[j + 2], sn3 = cs[j + 3];
        float e0 = el[sn0 * H + h] + erh;
        float e1 = el[sn1 * H + h] + erh;
        float e2 = el[sn2 * H + h] + erh;
        float e3 = el[sn3 * H + h] + erh;
        e0 = e0 > 0.f ? e0 : 0.2f * e0;
        e1 = e1 > 0.f ? e1 : 0.2f * e1;
        e2 = e2 > 0.f ? e2 : 0.2f * e2;
        e3 = e3 > 0.f ? e3 : 0.2f * e3;
        float p0 = __expf(e0), p1 = __expf(e1), p2 = __expf(e2), p3 = __expf(e3);
        s += (p0 + p1) + (p2 + p3);
        if constexpr (PL == 2) {
            float2 f0 = __bfloat1622float2(*(const __hip_bfloat162*)&feat[sn0 * DOUT + lane * 2]);
            float2 f1 = __bfloat1622float2(*(const __hip_bfloat162*)&feat[sn1 * DOUT + lane * 2]);
            float2 f2 = __bfloat1622float2(*(const __hip_bfloat162*)&feat[sn2 * DOUT + lane * 2]);
            float2 f3 = __bfloat1622float2(*(const __hip_bfloat162*)&feat[sn3 * DOUT + lane * 2]);
            a0 += p0 * f0.x + p1 * f1.x + p2 * f2.x + p3 * f3.x;
            a1 += p0 * f0.y + p1 * f1.y + p2 * f2.y + p3 * f3.y;
        } else {
            a0 += p0 * __bfloat162float(feat[sn0 * DOUT + lane])
                + p1 * __bfloat162float(feat[sn1 * DOUT + lane])
                + p2 * __bfloat162float(feat[sn2 * DOUT + lane])
                + p3 * __bfloat162float(feat[sn3 * DOUT + lane]);
        }
    }
    for (; j < deg; j++) {
        int sn0 = cs[j];
        float e0 = el[sn0 * H + h] + erh;
        e0 = e0 > 0.f ? e0 : 0.2f * e0;
        float p0 = __expf(e0);
        s += p0;
        if constexpr (PL == 2) {
            float2 f0 = __bfloat1622float2(*(const __hip_bfloat162*)&feat[sn0 * DOUT + lane * 2]);
            a0 += p0 * f0.x;
            a1 += p0 * f0.y;
        } else {
            a0 += p0 * __bfloat162float(feat[sn0 * DOUT + lane]);
        }
    }

    const float inv = (s > 0.f) ? 1.f / s : 0.f;
    if constexpr (PL == 2) {
        float v0 = a0 * inv + b[lane * 2];
        float v1 = a1 * inv + b[lane * 2 + 1];
        if (do_elu) {
            v0 = v0 > 0.f ? v0 : expm1f(v0);
            v1 = v1 > 0.f ? v1 : expm1f(v1);
        }
        float2 o = {v0, v1};
        *(float2*)&xout[n * DOUT + lane * 2] = o;
    } else {
        float v0 = a0 * inv + b[lane];
        if (do_elu) v0 = v0 > 0.f ? v0 : expm1f(v0);
        xout[n * DOUT + lane] = v0;
    }
}

// ================= launch =================
extern "C" void kernel_launch(void* const* d_in, const int* in_sizes, int n_in,
                              void* d_out, int out_size, void* d_ws, size_t ws_size,
                              hipStream_t stream) {
    const float* h   = (const float*)d_in[0];
    const int*   src = (const int*)d_in[1];
    const int*   dst = (const int*)d_in[2];
    const float* W1  = (const float*)d_in[3];
    const float* al1 = (const float*)d_in[4];
    const float* ar1 = (const float*)d_in[5];
    const float* b1  = (const float*)d_in[6];
    const float* W2  = (const float*)d_in[7];
    const float* al2 = (const float*)d_in[8];
    const float* ar2 = (const float*)d_in[9];
    const float* b2  = (const float*)d_in[10];
    const float* W3  = (const float*)d_in[11];
    const float* al3 = (const float*)d_in[12];
    const float* ar3 = (const float*)d_in[13];
    const float* b3  = (const float*)d_in[14];

    char* w = (char*)d_ws;
    __hip_bfloat16* feat = (__hip_bfloat16*)w;  w += (size_t)NNODES * 128 * 2;
    float* x2 = (float*)w;                      w += (size_t)NNODES * 128 * 4;
    float* x3 = (float*)w;                      w += (size_t)NNODES * 128 * 4;
    float* el = (float*)w;                      w += (size_t)NNODES * 4 * 4;
    float* er = (float*)w;                      w += (size_t)NNODES * 4 * 4;
    int* deg     = (int*)w;                     w += (size_t)NNODES * 4;
    int* rowptr  = (int*)w;                     w += (size_t)(NNODES + 4) * 4;
    int* cursor  = (int*)w;                     w += (size_t)NNODES * 4;
    int* csr_src = (int*)w;

    const dim3 B(256);

    // ---- CSR build (graph is layer-invariant) ----
    zero_deg<<<cdiv(NNODES, 256), B, 0, stream>>>(deg);
    count_deg<<<cdiv(NEDGES, 256), B, 0, stream>>>(dst, deg);
    scan_rowptr<<<1, 1024, 0, stream>>>(deg, rowptr, cursor);
    scatter_src<<<cdiv(NEDGES, 256), B, 0, stream>>>(src, dst, cursor, csr_src);

    // ---- layer 1 (H=4, D=32, DOUT=128) ----
    gemm_attn_rt2<128, 4><<<cdiv(NNODES, 128), B, 0, stream>>>(h, W1, al1, ar1, feat, el, er);
    node_aggregate3<128, 4><<<cdiv(NNODES, 4), B, 0, stream>>>(rowptr, csr_src, el, er, feat, b1, x2, 1);

    // ---- layer 2 (H=4, D=32, DOUT=128) ----
    gemm_attn_rt2<128, 4><<<cdiv(NNODES, 128), B, 0, stream>>>(x2, W2, al2, ar2, feat, el, er);
    node_aggregate3<128, 4><<<cdiv(NNODES, 4), B, 0, stream>>>(rowptr, csr_src, el, er, feat, b2, x3, 1);

    // ---- layer 3 (H=1, D=64, DOUT=64) ----
    gemm_attn_rt2<64, 1><<<cdiv(NNODES, 128), B, 0, stream>>>(x3, W3, al3, ar3, feat, el, er);
    node_aggregate3<64, 1><<<cdiv(NNODES, 4), B, 0, stream>>>(rowptr, csr_src, el, er, feat, b3, (float*)d_out, 0);
}

// Round 13
// 420.206 us; speedup vs baseline: 3.2647x; 1.0300x over previous
//
#include <hip/hip_runtime.h>
#include <hip/hip_bf16.h>
#include <math.h>

#define NNODES 50000
#define NEDGES 800000

static inline int cdiv(int a, int b) { return (a + b - 1) / b; }

// ================= CSR build (once per call; graph shared by all layers) =================

__global__ void zero_deg(int* __restrict__ deg) {
    int i = blockIdx.x * blockDim.x + threadIdx.x;
    if (i < NNODES) deg[i] = 0;
}

__global__ void count_deg(const int* __restrict__ dst, int* __restrict__ deg) {
    int e = blockIdx.x * blockDim.x + threadIdx.x;
    if (e < NEDGES) atomicAdd(&deg[dst[e]], 1);
}

// single-block exclusive scan, 4 elems/thread -> rowptr[0..N], cursor copy
__global__ void scan_rowptr(const int* __restrict__ deg, int* __restrict__ rowptr,
                            int* __restrict__ cursor) {
    __shared__ int wsum[16];
    __shared__ int wpre[16];
    const int tid = threadIdx.x;
    const int lane = tid & 63, wid = tid >> 6;
    int carry = 0;
    const int ntiles = (NNODES + 4095) / 4096;
    for (int t = 0; t < ntiles; t++) {
        int i0 = t * 4096 + tid * 4;
        int4 v = make_int4(0, 0, 0, 0);
        if (i0 < NNODES) v = *(const int4*)&deg[i0];   // NNODES % 4 == 0
        int lsum = v.x + v.y + v.z + v.w;
        int x = lsum;
#pragma unroll
        for (int off = 1; off < 64; off <<= 1) {
            int y = __shfl_up(x, off);
            if (lane >= off) x += y;
        }
        if (lane == 63) wsum[wid] = x;
        __syncthreads();
        if (wid == 0) {
            int w = (lane < 16) ? wsum[lane] : 0;
            int xs = w;
#pragma unroll
            for (int off = 1; off < 16; off <<= 1) {
                int y = __shfl_up(xs, off);
                if (lane >= off) xs += y;
            }
            if (lane < 16) wpre[lane] = xs - w;   // exclusive wave prefix
        }
        __syncthreads();
        int excl = carry + wpre[wid] + x - lsum;
        if (i0 < NNODES) {
            int4 r;
            r.x = excl; r.y = r.x + v.x; r.z = r.y + v.y; r.w = r.z + v.z;
            *(int4*)&rowptr[i0] = r;
            *(int4*)&cursor[i0] = r;
        }
        carry += wpre[15] + wsum[15];
        __syncthreads();
    }
    if (tid == 0) rowptr[NNODES] = carry;
}

__global__ void scatter_src(const int* __restrict__ src, const int* __restrict__ dst,
                            int* __restrict__ cursor, int* __restrict__ csr_src) {
    int e = blockIdx.x * blockDim.x + threadIdx.x;
    if (e < NEDGES) {
        int pos = atomicAdd(&cursor[dst[e]], 1);
        csr_src[pos] = src[e];
    }
}

// ====== register-tiled fp32 GEMM (x @ W) + attention projections; feat written bf16 ======
// 256 threads, BMxDOUT tile, BK=32, 4x8 register tile/thread, 25KB LDS.
// BM=64 for DOUT=128 (grid 782), BM=128 for DOUT=64 (grid 391): occupancy-driven
// (BM=128/DOUT=128 was 391 blocks = 1.5 waves/SIMD -> latency-bound, 13% occupancy).
template <int BM, int DOUT, int H>
__global__ __launch_bounds__(256) void gemm_attn_rt2(
    const float* __restrict__ x, const float* __restrict__ W,
    const float* __restrict__ al, const float* __restrict__ ar,
    __hip_bfloat16* __restrict__ feat, float* __restrict__ el,
    float* __restrict__ er) {
    constexpr int BK = 32;
    constexpr int NC = 8;                 // cols per thread
    constexpr int CG = DOUT / NC;         // col groups (16 or 8)
    constexpr int NG = 256 / CG;          // node groups (16 or 32)
    constexpr int NT = BM / NG;           // nodes per thread (4)
    constexpr int D = DOUT / H;           // dims per head
    constexpr int CPH = D / NC;           // col-groups per head (4 or 8)
    constexpr int XP = BM + 4;            // padded x_t stride (16B-aligned rows)
    static_assert(NT == 4, "tile assumes 4 nodes/thread");

    __shared__ float xs[BK][XP];
    __shared__ float ws[BK][DOUT];

    const int t = threadIdx.x;
    const int node0 = blockIdx.x * BM;
    const int cg = t % CG, ng = t / CG;
    const int c0 = cg * NC, n0 = ng * NT;

    float acc[NT][NC];
#pragma unroll
    for (int i = 0; i < NT; i++)
#pragma unroll
        for (int j = 0; j < NC; j++) acc[i][j] = 0.f;

    for (int k0 = 0; k0 < 128; k0 += BK) {
        // stage W k-slice (coalesced float4)
        for (int i = t * 4; i < BK * DOUT; i += 256 * 4) {
            int kk = i / DOUT, c = i % DOUT;
            *(float4*)&ws[kk][c] = *(const float4*)&W[(k0 + kk) * DOUT + c];
        }
        // stage x transposed (coalesced global read)
        for (int i = t; i < BK * BM; i += 256) {
            int kk = i & (BK - 1), nd = i >> 5;
            int node = node0 + nd;
            xs[kk][nd] = (node < NNODES) ? x[node * 128 + k0 + kk] : 0.f;
        }
        __syncthreads();
        for (int k = 0; k < BK; k++) {
            const float4 wa = *(const float4*)&ws[k][c0];
            const float4 wb = *(const float4*)&ws[k][c0 + 4];
            float wv[NC] = {wa.x, wa.y, wa.z, wa.w, wb.x, wb.y, wb.z, wb.w};
            const float4 xv = *(const float4*)&xs[k][n0];
            float xvv[4] = {xv.x, xv.y, xv.z, xv.w};
#pragma unroll
            for (int ii = 0; ii < 4; ii++)
#pragma unroll
                for (int q = 0; q < NC; q++)
                    acc[ii][q] += xvv[ii] * wv[q];
        }
        __syncthreads();
    }

    // epilogue: feat (bf16x8), el/er via shfl-reduce over the head's col-groups
    const float4 ala = *(const float4*)&al[c0];
    const float4 alb = *(const float4*)&al[c0 + 4];
    const float4 ara = *(const float4*)&ar[c0];
    const float4 arb = *(const float4*)&ar[c0 + 4];
    const float alv[NC] = {ala.x, ala.y, ala.z, ala.w, alb.x, alb.y, alb.z, alb.w};
    const float arv[NC] = {ara.x, ara.y, ara.z, ara.w, arb.x, arb.y, arb.z, arb.w};
    const int head = c0 / D;
#pragma unroll
    for (int i = 0; i < NT; i++) {
        const int node = node0 + n0 + i;
        float pl = 0.f, pr = 0.f;
        if (node < NNODES) {
            ushort4 u0, u1;
            u0.x = __bfloat16_as_ushort(__float2bfloat16(acc[i][0]));
            u0.y = __bfloat16_as_ushort(__float2bfloat16(acc[i][1]));
            u0.z = __bfloat16_as_ushort(__float2bfloat16(acc[i][2]));
            u0.w = __bfloat16_as_ushort(__float2bfloat16(acc[i][3]));
            u1.x = __bfloat16_as_ushort(__float2bfloat16(acc[i][4]));
            u1.y = __bfloat16_as_ushort(__float2bfloat16(acc[i][5]));
            u1.z = __bfloat16_as_ushort(__float2bfloat16(acc[i][6]));
            u1.w = __bfloat16_as_ushort(__float2bfloat16(acc[i][7]));
            *(ushort4*)&feat[node * DOUT + c0] = u0;
            *(ushort4*)&feat[node * DOUT + c0 + 4] = u1;
        }
#pragma unroll
        for (int q = 0; q < NC; q++) {
            pl += acc[i][q] * alv[q];
            pr += acc[i][q] * arv[q];
        }
#pragma unroll
        for (int off = CPH / 2; off > 0; off >>= 1) {
            pl += __shfl_xor(pl, off);
            pr += __shfl_xor(pr, off);
        }
        if ((cg % CPH) == 0 && node < NNODES) {
            el[node * H + head] = pl;
            er[node * H + head] = pr;
        }
    }
}

// ========== per-node softmax + aggregation (no atomics, 4x unroll, fp32 out) ==========
template <int DOUT, int H>
__global__ __launch_bounds__(256) void node_aggregate3(
    const int* __restrict__ rowptr, const int* __restrict__ csr_src,
    const float* __restrict__ el, const float* __restrict__ er,
    const __hip_bfloat16* __restrict__ feat, const float* __restrict__ b,
    float* __restrict__ xout, int do_elu) {
    constexpr int D = DOUT / H;        // dims per head
    constexpr int PL = DOUT / 64;      // dims per lane (2 or 1)
    const int lane = threadIdx.x & 63;
    const int wid = threadIdx.x >> 6;
    const int n = blockIdx.x * 4 + wid;
    if (n >= NNODES) return;
    const int base = rowptr[n];
    const int deg = rowptr[n + 1] - base;

    const int h = (lane * PL) / D;     // head owning this lane's dims
    const float erh = er[n * H + h];
    const int* cs = &csr_src[base];

    float s = 0.f;
    float a0 = 0.f, a1 = 0.f;

    int j = 0;
    for (; j + 3 < deg; j += 4) {
        int sn0 = cs[j], sn1 = cs[j + 1], sn2 = cs[j + 2], sn3 = cs[j + 3];
        float e0 = el[sn0 * H + h] + erh;
        float e1 = el[sn1 * H + h] + erh;
        float e2 = el[sn2 * H + h] + erh;
        float e3 = el[sn3 * H + h] + erh;
        e0 = e0 > 0.f ? e0 : 0.2f * e0;
        e1 = e1 > 0.f ? e1 : 0.2f * e1;
        e2 = e2 > 0.f ? e2 : 0.2f * e2;
        e3 = e3 > 0.f ? e3 : 0.2f * e3;
        float p0 = __expf(e0), p1 = __expf(e1), p2 = __expf(e2), p3 = __expf(e3);
        s += (p0 + p1) + (p2 + p3);
        if constexpr (PL == 2) {
            float2 f0 = __bfloat1622float2(*(const __hip_bfloat162*)&feat[sn0 * DOUT + lane * 2]);
            float2 f1 = __bfloat1622float2(*(const __hip_bfloat162*)&feat[sn1 * DOUT + lane * 2]);
            float2 f2 = __bfloat1622float2(*(const __hip_bfloat162*)&feat[sn2 * DOUT + lane * 2]);
            float2 f3 = __bfloat1622float2(*(const __hip_bfloat162*)&feat[sn3 * DOUT + lane * 2]);
            a0 += p0 * f0.x + p1 * f1.x + p2 * f2.x + p3 * f3.x;
            a1 += p0 * f0.y + p1 * f1.y + p2 * f2.y + p3 * f3.y;
        } else {
            a0 += p0 * __bfloat162float(feat[sn0 * DOUT + lane])
                + p1 * __bfloat162float(feat[sn1 * DOUT + lane])
                + p2 * __bfloat162float(feat[sn2 * DOUT + lane])
                + p3 * __bfloat162float(feat[sn3 * DOUT + lane]);
        }
    }
    for (; j < deg; j++) {
        int sn0 = cs[j];
        float e0 = el[sn0 * H + h] + erh;
        e0 = e0 > 0.f ? e0 : 0.2f * e0;
        float p0 = __expf(e0);
        s += p0;
        if constexpr (PL == 2) {
            float2 f0 = __bfloat1622float2(*(const __hip_bfloat162*)&feat[sn0 * DOUT + lane * 2]);
            a0 += p0 * f0.x;
            a1 += p0 * f0.y;
        } else {
            a0 += p0 * __bfloat162float(feat[sn0 * DOUT + lane]);
        }
    }

    const float inv = (s > 0.f) ? 1.f / s : 0.f;
    if constexpr (PL == 2) {
        float v0 = a0 * inv + b[lane * 2];
        float v1 = a1 * inv + b[lane * 2 + 1];
        if (do_elu) {
            v0 = v0 > 0.f ? v0 : expm1f(v0);
            v1 = v1 > 0.f ? v1 : expm1f(v1);
        }
        float2 o = {v0, v1};
        *(float2*)&xout[n * DOUT + lane * 2] = o;
    } else {
        float v0 = a0 * inv + b[lane];
        if (do_elu) v0 = v0 > 0.f ? v0 : expm1f(v0);
        xout[n * DOUT + lane] = v0;
    }
}

// ================= launch =================
extern "C" void kernel_launch(void* const* d_in, const int* in_sizes, int n_in,
                              void* d_out, int out_size, void* d_ws, size_t ws_size,
                              hipStream_t stream) {
    const float* h   = (const float*)d_in[0];
    const int*   src = (const int*)d_in[1];
    const int*   dst = (const int*)d_in[2];
    const float* W1  = (const float*)d_in[3];
    const float* al1 = (const float*)d_in[4];
    const float* ar1 = (const float*)d_in[5];
    const float* b1  = (const float*)d_in[6];
    const float* W2  = (const float*)d_in[7];
    const float* al2 = (const float*)d_in[8];
    const float* ar2 = (const float*)d_in[9];
    const float* b2  = (const float*)d_in[10];
    const float* W3  = (const float*)d_in[11];
    const float* al3 = (const float*)d_in[12];
    const float* ar3 = (const float*)d_in[13];
    const float* b3  = (const float*)d_in[14];

    char* w = (char*)d_ws;
    __hip_bfloat16* feat = (__hip_bfloat16*)w;  w += (size_t)NNODES * 128 * 2;
    float* x2 = (float*)w;                      w += (size_t)NNODES * 128 * 4;
    float* x3 = (float*)w;                      w += (size_t)NNODES * 128 * 4;
    float* el = (float*)w;                      w += (size_t)NNODES * 4 * 4;
    float* er = (float*)w;                      w += (size_t)NNODES * 4 * 4;
    int* deg     = (int*)w;                     w += (size_t)NNODES * 4;
    int* rowptr  = (int*)w;                     w += (size_t)(NNODES + 4) * 4;
    int* cursor  = (int*)w;                     w += (size_t)NNODES * 4;
    int* csr_src = (int*)w;

    const dim3 B(256);

    // ---- CSR build (graph is layer-invariant) ----
    zero_deg<<<cdiv(NNODES, 256), B, 0, stream>>>(deg);
    count_deg<<<cdiv(NEDGES, 256), B, 0, stream>>>(dst, deg);
    scan_rowptr<<<1, 1024, 0, stream>>>(deg, rowptr, cursor);
    scatter_src<<<cdiv(NEDGES, 256), B, 0, stream>>>(src, dst, cursor, csr_src);

    // ---- layer 1 (H=4, D=32, DOUT=128) ----
    gemm_attn_rt2<64, 128, 4><<<cdiv(NNODES, 64), B, 0, stream>>>(h, W1, al1, ar1, feat, el, er);
    node_aggregate3<128, 4><<<cdiv(NNODES, 4), B, 0, stream>>>(rowptr, csr_src, el, er, feat, b1, x2, 1);

    // ---- layer 2 (H=4, D=32, DOUT=128) ----
    gemm_attn_rt2<64, 128, 4><<<cdiv(NNODES, 64), B, 0, stream>>>(x2, W2, al2, ar2, feat, el, er);
    node_aggregate3<128, 4><<<cdiv(NNODES, 4), B, 0, stream>>>(rowptr, csr_src, el, er, feat, b2, x3, 1);

    // ---- layer 3 (H=1, D=64, DOUT=64) ----
    gemm_attn_rt2<128, 64, 1><<<cdiv(NNODES, 128), B, 0, stream>>>(x3, W3, al3, ar3, feat, el, er);
    node_aggregate3<64, 1><<<cdiv(NNODES, 4), B, 0, stream>>>(rowptr, csr_src, el, er, feat, b3, (float*)d_out, 0);
}